// Round 5
// baseline (262.991 us; speedup 1.0000x reference)
//
#include <hip/hip_runtime.h>

typedef unsigned short ushort_t;
typedef unsigned int uint_t;

typedef short bf16x8 __attribute__((ext_vector_type(8)));
typedef float f32x4 __attribute__((ext_vector_type(4)));

#define MFMA16(a, b, c) __builtin_amdgcn_mfma_f32_16x16x32_bf16(a, b, c, 0, 0, 0)

__device__ __forceinline__ ushort_t f2bf(float f) {
    uint_t u = __float_as_uint(f);
    u += 0x7fffu + ((u >> 16) & 1u);   // RNE
    return (ushort_t)(u >> 16);
}
__device__ __forceinline__ float bf2f(ushort_t h) {
    return __uint_as_float(((uint_t)h) << 16);
}

// async global->LDS, 16B per lane; lds dst is wave-uniform (HW adds lane*16)
__device__ __forceinline__ void async16(const ushort_t* g, ushort_t* l) {
    __builtin_amdgcn_global_load_lds(
        (const __attribute__((address_space(1))) uint_t*)g,
        (__attribute__((address_space(3))) uint_t*)l, 16, 0, 0);
}

// ---------------- K0: fused prep. block0: const_h; blocks 1..128: Wa->bf16 blocked;
// blocks 129..144: Ws1[:, :256] -> bf16 hi/lo blocked.
// blocked flat (in 8-elem units): ((row/16)*32 + k/8)*16 + row%16
__global__ void k_prep(const float* __restrict__ Ws1, const float* __restrict__ bs1,
                       const float* __restrict__ virt, const float* __restrict__ Wa,
                       float* __restrict__ consth, ushort_t* __restrict__ wa_b,
                       ushort_t* __restrict__ ws1h, ushort_t* __restrict__ ws1l) {
    int b = blockIdx.x;
    if (b == 0) {
        int h = threadIdx.x;
        if (h < 128) {
            const float* row = Ws1 + h * 512 + 256;
            float s = bs1[h];
            for (int d = 0; d < 256; ++d) s += row[d] * virt[d];
            consth[h] = s;
        }
        return;
    }
    const float* src;
    int src_stride, tid;
    ushort_t *dhi, *dlo;
    if (b <= 128) {
        tid = (b - 1) * 256 + threadIdx.x;   // 1024 rows * 32 = 32768 tids
        src = Wa; src_stride = 256; dhi = wa_b; dlo = nullptr;
    } else {
        tid = (b - 129) * 256 + threadIdx.x; // 128 rows * 32 = 4096 tids
        src = Ws1; src_stride = 512; dhi = ws1h; dlo = ws1l;
    }
    int pl = tid & 15, kc = (tid >> 4) & 31, pt = tid >> 9;
    int row = pt * 16 + pl;
    const float* s = src + (size_t)row * src_stride + kc * 8;
    ushort_t hs[8], ls[8];
#pragma unroll
    for (int j = 0; j < 8; ++j) {
        float v = s[j];
        ushort_t h = f2bf(v);
        hs[j] = h;
        ls[j] = f2bf(v - bf2f(h));
    }
    uint4 hv;
    hv.x = hs[0] | ((uint_t)hs[1] << 16); hv.y = hs[2] | ((uint_t)hs[3] << 16);
    hv.z = hs[4] | ((uint_t)hs[5] << 16); hv.w = hs[6] | ((uint_t)hs[7] << 16);
    *(uint4*)(dhi + (size_t)tid * 8) = hv;
    if (dlo) {
        uint4 lv;
        lv.x = ls[0] | ((uint_t)ls[1] << 16); lv.y = ls[2] | ((uint_t)ls[3] << 16);
        lv.z = ls[4] | ((uint_t)ls[5] << 16); lv.w = ls[6] | ((uint_t)ls[7] << 16);
        *(uint4*)(dlo + (size_t)tid * 8) = lv;
    }
}

// ---------------- K1: FUSED embed + struct head.
// LDS region is ALIASED: phase 1-2 it holds the 64 staged q-rows (64x1040B);
// fragments are held in 64 VGPRs across a barrier, then the same region becomes
// sAhi|sAlo for the block-wide MFMA exchange. 67 KB total -> 2 blocks/CU.
__global__ __launch_bounds__(256, 2) void k_embed_struct(
    const int* __restrict__ q_seq, const int* __restrict__ r_seq,
    const float* __restrict__ t_seq, const float* __restrict__ q_tab,
    const float* __restrict__ r_tab,
    const ushort_t* __restrict__ ws1h, const ushort_t* __restrict__ ws1l,
    const float* __restrict__ consth, const float* __restrict__ Ws2,
    const float* __restrict__ bs2, const float* __restrict__ mask,
    ushort_t* __restrict__ h_hi, float* __restrict__ out_ahat) {
    __shared__ __align__(16) char region[66560];   // sQ (64x520 us)  ∪  sAhi+sAlo
    __shared__ float sdiv[128];
    __shared__ float sLogit[64];
    ushort_t* sQ = (ushort_t*)region;
    ushort_t* sAhi = (ushort_t*)region;
    ushort_t* sAlo = (ushort_t*)(region + 32768);
    int tid = threadIdx.x;
    if (tid < 128) sdiv[tid] = __expf((float)tid * -0.07195578415606394f); // -ln(10000)/128
    if (tid < 64) sLogit[tid] = 0.0f;
    int w = tid >> 6, lane = tid & 63;
    int pl = lane & 15, kq = lane >> 4;
    int nl = pl;
    int p0 = blockIdx.x * 64;
    int p = p0 + w * 16 + pl;
    int qv = q_seq[p0 + w * 16 + pl];
    int rr = r_seq[p];
    float tt = t_seq[p];
    // stage this wave's 16 q-rows into LDS (each async16 = one full 1KB row, coalesced)
#pragma unroll
    for (int i = 0; i < 16; ++i) {
        int row = __shfl(qv, i, 64);
        async16((const ushort_t*)(q_tab + (size_t)row * 256) + lane * 8,
                sQ + (w * 16 + i) * 520);
    }
    __syncthreads();  // q-rows + sdiv + sLogit ready (barrier drains vmcnt)
    // phase 2: compute fragments into REGISTERS (sQ still live)
    uint4 hvA[8], lvA[8];
    const char* myrow = (const char*)sQ + (w * 16 + pl) * 1040;
    const float* rrow = r_tab + (size_t)rr * 256;
#pragma unroll
    for (int it = 0; it < 8; ++it) {
        int kc = it * 4 + kq;
        int k0 = kc * 8;
        float4 qa = *(const float4*)(myrow + kc * 32);
        float4 qb = *(const float4*)(myrow + kc * 32 + 16);
        float4 ra = *(const float4*)(rrow + kc * 8);
        float4 rb = *(const float4*)(rrow + kc * 8 + 4);
        float v[8] = {qa.x + ra.x, qa.y + ra.y, qa.z + ra.z, qa.w + ra.w,
                      qb.x + rb.x, qb.y + rb.y, qb.z + rb.z, qb.w + rb.w};
        bool iscos = (kc >= 16);
#pragma unroll
        for (int j = 0; j < 8; ++j) {
            float ang = tt * sdiv[(k0 + j) & 127];
            v[j] += iscos ? __cosf(ang) : __sinf(ang);
        }
        ushort_t hs[8], ls[8];
#pragma unroll
        for (int j = 0; j < 8; ++j) {
            ushort_t h = f2bf(v[j]);
            hs[j] = h;
            ls[j] = f2bf(v[j] - bf2f(h));
        }
        uint4 hv, lv;
        hv.x = hs[0] | ((uint_t)hs[1] << 16); hv.y = hs[2] | ((uint_t)hs[3] << 16);
        hv.z = hs[4] | ((uint_t)hs[5] << 16); hv.w = hs[6] | ((uint_t)hs[7] << 16);
        lv.x = ls[0] | ((uint_t)ls[1] << 16); lv.y = ls[2] | ((uint_t)ls[3] << 16);
        lv.z = ls[4] | ((uint_t)ls[5] << 16); lv.w = ls[6] | ((uint_t)ls[7] << 16);
        hvA[it] = hv; lvA[it] = lv;
        *(uint4*)(h_hi + ((size_t)((blockIdx.x * 4 + w) * 32 + kc) * 16 + pl) * 8) = hv;
    }
    __syncthreads();  // all sQ reads complete -> region can be re-purposed
#pragma unroll
    for (int it = 0; it < 8; ++it) {
        int kc = it * 4 + kq;
        int loff = ((w * 32 + kc) * 16 + pl) * 8;
        *(uint4*)(sAhi + loff) = hvA[it];
        *(uint4*)(sAlo + loff) = lvA[it];
    }
    __syncthreads();  // fragments visible block-wide
    f32x4 acc[4][2];
    f32x4 z4 = {0.f, 0.f, 0.f, 0.f};
#pragma unroll
    for (int mt = 0; mt < 4; ++mt)
#pragma unroll
        for (int nt = 0; nt < 2; ++nt) acc[mt][nt] = z4;
    // software-pipelined B loads from global (L2-hot, coalesced 1KB/wave)
    bf16x8 bhi[2], blo[2], nbhi[2], nblo[2];
#pragma unroll
    for (int nt = 0; nt < 2; ++nt) {
        int off = (((w * 2 + nt) * 32 + kq) * 16 + nl) * 8;
        bhi[nt] = *(const bf16x8*)(ws1h + off);
        blo[nt] = *(const bf16x8*)(ws1l + off);
    }
#pragma unroll 1
    for (int ks = 0; ks < 8; ++ks) {
        if (ks < 7) {
#pragma unroll
            for (int nt = 0; nt < 2; ++nt) {
                int off = (((w * 2 + nt) * 32 + (ks + 1) * 4 + kq) * 16 + nl) * 8;
                nbhi[nt] = *(const bf16x8*)(ws1h + off);
                nblo[nt] = *(const bf16x8*)(ws1l + off);
            }
        }
        bf16x8 ahi[4], alo[4];
#pragma unroll
        for (int mt = 0; mt < 4; ++mt) {
            int off = ((mt * 32 + ks * 4 + kq) * 16 + nl) * 8;
            ahi[mt] = *(const bf16x8*)&sAhi[off];
            alo[mt] = *(const bf16x8*)&sAlo[off];
        }
#pragma unroll
        for (int mt = 0; mt < 4; ++mt)
#pragma unroll
            for (int nt = 0; nt < 2; ++nt) {
                acc[mt][nt] = MFMA16(ahi[mt], bhi[nt], acc[mt][nt]);
                acc[mt][nt] = MFMA16(alo[mt], bhi[nt], acc[mt][nt]);
                acc[mt][nt] = MFMA16(ahi[mt], blo[nt], acc[mt][nt]);
            }
#pragma unroll
        for (int nt = 0; nt < 2; ++nt) { bhi[nt] = nbhi[nt]; blo[nt] = nblo[nt]; }
    }
    // epilogue: hdn = leaky(acc + const_h); partial logits = hdn * Ws2
    float ps[4][4];
#pragma unroll
    for (int mt = 0; mt < 4; ++mt)
#pragma unroll
        for (int r = 0; r < 4; ++r) ps[mt][r] = 0.f;
#pragma unroll
    for (int nt = 0; nt < 2; ++nt) {
        int ng = w * 32 + nt * 16 + nl;
        float chv = consth[ng], w2 = Ws2[ng];
#pragma unroll
        for (int mt = 0; mt < 4; ++mt)
#pragma unroll
            for (int r = 0; r < 4; ++r) {
                float v = acc[mt][nt][r] + chv;
                v = v > 0.f ? v : 0.2f * v;
                ps[mt][r] += v * w2;
            }
    }
#pragma unroll
    for (int mt = 0; mt < 4; ++mt)
#pragma unroll
        for (int r = 0; r < 4; ++r) {
            float x = ps[mt][r];
            x += __shfl_xor(x, 1, 64);
            x += __shfl_xor(x, 2, 64);
            x += __shfl_xor(x, 4, 64);
            x += __shfl_xor(x, 8, 64);
            ps[mt][r] = x;
        }
    if (nl == 0) {
#pragma unroll
        for (int mt = 0; mt < 4; ++mt)
#pragma unroll
            for (int r = 0; r < 4; ++r)
                atomicAdd(&sLogit[mt * 16 + kq * 4 + r], ps[mt][r]);
    }
    __syncthreads();
    if (tid < 64) {
        int pp = p0 + tid;
        float lg = sLogit[tid] + bs2[0];
        float y = lg * 100.0f;
        y = fminf(fmaxf(y, -60.f), 60.f);
        float a = 1.0f / (1.0f + expf(-y));
        out_ahat[pp] = a * mask[pp];
    }
}

// ---------------- K2: Wa GEMM, BARRIER-FREE K-loop. A-fragments register-resident
// (32 coalesced dwordx4, loaded once). B-fragments loaded straight from global
// (L2-resident 512KB, perfectly coalesced 1KB/wave per fragment) with depth-1
// software prefetch. One __syncthreads total (sAh). Fused leaky + A_hat + L-reduce.
__global__ __launch_bounds__(256, 2) void k_agg(
    const ushort_t* __restrict__ h_hi, const ushort_t* __restrict__ wa_blk,
    const float* __restrict__ ba, const float* __restrict__ ahat,
    float* __restrict__ u_i) {
    __shared__ float sAh[128];
    int tid = threadIdx.x;
    int w = tid >> 6, lane = tid & 63, nl = lane & 15, kq = lane >> 4;
    int p0 = blockIdx.x * 128, bidx = p0 >> 11;
    if (tid < 128) sAh[tid] = ahat[p0 + tid];
    int mh = w & 1, nh = w >> 1;
    // A fragments: wave's 64 rows x all 256 K -> 32 coalesced 16B loads (resident)
    bf16x8 afr[4][8];
    const ushort_t* gA = h_hi + (size_t)(p0 >> 4) * 4096;
#pragma unroll
    for (int mt = 0; mt < 4; ++mt) {
        const ushort_t* base = gA + (size_t)(mh * 4 + mt) * 4096;
#pragma unroll
        for (int ks = 0; ks < 8; ++ks)
            afr[mt][ks] = *(const bf16x8*)(base + ks * 512 + lane * 8);
    }
    __syncthreads();  // sAh ready (the only barrier)
    // wave's B base: its n-half of the current n-chunk
    const ushort_t* gBw = wa_blk + (size_t)nh * 4 * 4096 + lane * 8;
#pragma unroll 1
    for (int nch = 0; nch < 8; ++nch) {
        const ushort_t* gB = gBw + (size_t)nch * 32768;
        f32x4 acc[4][4];
        bf16x8 bcur[4], bnxt[4];
#pragma unroll
        for (int nt = 0; nt < 4; ++nt)
            bcur[nt] = *(const bf16x8*)(gB + nt * 4096);
#pragma unroll
        for (int ks = 0; ks < 8; ++ks) {
            if (ks < 7) {
#pragma unroll
                for (int nt = 0; nt < 4; ++nt)
                    bnxt[nt] = *(const bf16x8*)(gB + nt * 4096 + (ks + 1) * 512);
            }
            if (ks == 0) {
                f32x4 z4 = {0.f, 0.f, 0.f, 0.f};
#pragma unroll
                for (int mt = 0; mt < 4; ++mt)
#pragma unroll
                    for (int nt = 0; nt < 4; ++nt)
                        acc[mt][nt] = MFMA16(afr[mt][0], bcur[nt], z4);
            } else {
#pragma unroll
                for (int mt = 0; mt < 4; ++mt)
#pragma unroll
                    for (int nt = 0; nt < 4; ++nt)
                        acc[mt][nt] = MFMA16(afr[mt][ks], bcur[nt], acc[mt][nt]);
            }
#pragma unroll
            for (int nt = 0; nt < 4; ++nt) bcur[nt] = bnxt[nt];
        }
        // epilogue: leaky(acc+ba)*A_hat, reduce over the wave's 64 m-rows
        int n0 = nch * 128;
#pragma unroll
        for (int nt = 0; nt < 4; ++nt) {
            int ng = n0 + nh * 64 + nt * 16 + nl;
            float ban = ba[ng];
            float s = 0.f;
#pragma unroll
            for (int mt = 0; mt < 4; ++mt)
#pragma unroll
                for (int r = 0; r < 4; ++r) {
                    float v = acc[mt][nt][r] + ban;
                    v = v > 0.f ? v : 0.2f * v;
                    int ml = mh * 64 + mt * 16 + kq * 4 + r;
                    s += v * sAh[ml];
                }
            s += __shfl_xor(s, 16, 64);
            s += __shfl_xor(s, 32, 64);
            if (kq == 0) atomicAdd(&u_i[bidx * 1024 + ng], s);
        }
    }
}

extern "C" void kernel_launch(void* const* d_in, const int* in_sizes, int n_in,
                              void* d_out, int out_size, void* d_ws, size_t ws_size,
                              hipStream_t stream) {
    const int* q_seq = (const int*)d_in[0];
    const int* r_seq = (const int*)d_in[1];
    const float* t_seq = (const float*)d_in[2];
    const float* mask = (const float*)d_in[3];
    const float* q_tab = (const float*)d_in[4];
    const float* r_tab = (const float*)d_in[5];
    const float* virt = (const float*)d_in[6];
    const float* Ws1 = (const float*)d_in[7];
    const float* bs1 = (const float*)d_in[8];
    const float* Ws2 = (const float*)d_in[9];
    const float* bs2 = (const float*)d_in[10];
    const float* Wa = (const float*)d_in[11];
    const float* ba = (const float*)d_in[12];
    float* out = (float*)d_out;

    // ws layout
    ushort_t* h_hi = (ushort_t*)d_ws;            // 131072*256 bf16 blocked
    ushort_t* wa_b = h_hi + 33554432;            // 1024*256 bf16 blocked
    ushort_t* ws1h = wa_b + 262144;              // 128*256 bf16 blocked
    ushort_t* ws1l = ws1h + 32768;
    float* ch = (float*)(ws1l + 32768);          // 128 f32

    hipMemsetAsync(out, 0, 65536 * sizeof(float), stream);  // zero u_i
    hipLaunchKernelGGL(k_prep, dim3(145), dim3(256), 0, stream,
                       Ws1, bs1, virt, Wa, ch, wa_b, ws1h, ws1l);
    hipLaunchKernelGGL(k_embed_struct, dim3(2048), dim3(256), 0, stream,
                       q_seq, r_seq, t_seq, q_tab, r_tab, ws1h, ws1l, ch, Ws2, bs2,
                       mask, h_hi, out + 65536);
    hipLaunchKernelGGL(k_agg, dim3(1024), dim3(256), 0, stream,
                       h_hi, wa_b, ba, out + 65536, out);
}

// Round 6
// 251.739 us; speedup vs baseline: 1.0447x; 1.0447x over previous
//
#include <hip/hip_runtime.h>

typedef unsigned short ushort_t;
typedef unsigned int uint_t;

typedef short bf16x8 __attribute__((ext_vector_type(8)));
typedef float f32x4 __attribute__((ext_vector_type(4)));

#define MFMA16(a, b, c) __builtin_amdgcn_mfma_f32_16x16x32_bf16(a, b, c, 0, 0, 0)

__device__ __forceinline__ ushort_t f2bf(float f) {
    uint_t u = __float_as_uint(f);
    u += 0x7fffu + ((u >> 16) & 1u);   // RNE
    return (ushort_t)(u >> 16);
}
__device__ __forceinline__ float bf2f(ushort_t h) {
    return __uint_as_float(((uint_t)h) << 16);
}

// async global->LDS, 16B per lane; lds dst is wave-uniform (HW adds lane*16)
__device__ __forceinline__ void async16(const ushort_t* g, ushort_t* l) {
    __builtin_amdgcn_global_load_lds(
        (const __attribute__((address_space(1))) uint_t*)g,
        (__attribute__((address_space(3))) uint_t*)l, 16, 0, 0);
}

// ---------------- K0: fused prep. block0: const_h; blocks 1..128: Wa->bf16 blocked;
// blocks 129..144: Ws1[:, :256] -> bf16 hi/lo blocked.
// blocked flat (in 8-elem units): ((row/16)*32 + k/8)*16 + row%16
__global__ void k_prep(const float* __restrict__ Ws1, const float* __restrict__ bs1,
                       const float* __restrict__ virt, const float* __restrict__ Wa,
                       float* __restrict__ consth, ushort_t* __restrict__ wa_b,
                       ushort_t* __restrict__ ws1h, ushort_t* __restrict__ ws1l) {
    int b = blockIdx.x;
    if (b == 0) {
        int h = threadIdx.x;
        if (h < 128) {
            const float* row = Ws1 + h * 512 + 256;
            float s = bs1[h];
            for (int d = 0; d < 256; ++d) s += row[d] * virt[d];
            consth[h] = s;
        }
        return;
    }
    const float* src;
    int src_stride, tid;
    ushort_t *dhi, *dlo;
    if (b <= 128) {
        tid = (b - 1) * 256 + threadIdx.x;   // 1024 rows * 32 = 32768 tids
        src = Wa; src_stride = 256; dhi = wa_b; dlo = nullptr;
    } else {
        tid = (b - 129) * 256 + threadIdx.x; // 128 rows * 32 = 4096 tids
        src = Ws1; src_stride = 512; dhi = ws1h; dlo = ws1l;
    }
    int pl = tid & 15, kc = (tid >> 4) & 31, pt = tid >> 9;
    int row = pt * 16 + pl;
    const float* s = src + (size_t)row * src_stride + kc * 8;
    ushort_t hs[8], ls[8];
#pragma unroll
    for (int j = 0; j < 8; ++j) {
        float v = s[j];
        ushort_t h = f2bf(v);
        hs[j] = h;
        ls[j] = f2bf(v - bf2f(h));
    }
    uint4 hv;
    hv.x = hs[0] | ((uint_t)hs[1] << 16); hv.y = hs[2] | ((uint_t)hs[3] << 16);
    hv.z = hs[4] | ((uint_t)hs[5] << 16); hv.w = hs[6] | ((uint_t)hs[7] << 16);
    *(uint4*)(dhi + (size_t)tid * 8) = hv;
    if (dlo) {
        uint4 lv;
        lv.x = ls[0] | ((uint_t)ls[1] << 16); lv.y = ls[2] | ((uint_t)ls[3] << 16);
        lv.z = ls[4] | ((uint_t)ls[5] << 16); lv.w = ls[6] | ((uint_t)ls[7] << 16);
        *(uint4*)(dlo + (size_t)tid * 8) = lv;
    }
}

// ---------------- K1: FULLY FUSED embed + struct head + Wa-GEMM aggregator.
// Per block: 64 positions. Phases:
//  1) async16-stage 64 q-rows into LDS (aliased region)
//  2) gather+trig -> hi/lo fragments in regs (MFMA A-layout)
//  3) write frags to sAhi|sAlo (same region, after barrier)
//  4) struct head: split-bf16 MFMA + leaky + .Ws2 + sigmoid -> A_hat (LDS + global)
//  5) Wa GEMM: A-frags reg-resident from LDS, B streamed from L2 with copy-free
//     parity double-buffer; fused leaky+ba, *A_hat, m-reduce, atomicAdd u_i.
// h_events NEVER touches HBM.
__global__ __launch_bounds__(256, 2) void k_fused(
    const int* __restrict__ q_seq, const int* __restrict__ r_seq,
    const float* __restrict__ t_seq, const float* __restrict__ q_tab,
    const float* __restrict__ r_tab,
    const ushort_t* __restrict__ ws1h, const ushort_t* __restrict__ ws1l,
    const float* __restrict__ consth, const float* __restrict__ Ws2,
    const float* __restrict__ bs2, const float* __restrict__ mask,
    const ushort_t* __restrict__ wa_b, const float* __restrict__ ba,
    float* __restrict__ out_ahat, float* __restrict__ u_i) {
    __shared__ __align__(16) char region[66560];   // sQ (64x520 us) ∪ sAhi+sAlo
    __shared__ float sdiv[128];
    __shared__ float sLogit[64];
    __shared__ float sAh[64];
    ushort_t* sQ = (ushort_t*)region;
    ushort_t* sAhi = (ushort_t*)region;
    ushort_t* sAlo = (ushort_t*)(region + 32768);
    int tid = threadIdx.x;
    if (tid < 128) sdiv[tid] = __expf((float)tid * -0.07195578415606394f); // -ln(10000)/128
    if (tid < 64) sLogit[tid] = 0.0f;
    int w = tid >> 6, lane = tid & 63;
    int pl = lane & 15, kq = lane >> 4;
    int nl = pl;
    int p0 = blockIdx.x * 64;
    int p = p0 + w * 16 + pl;
    int qv = q_seq[p];
    int rr = r_seq[p];
    float tt = t_seq[p];
    // ---- phase 1: stage this wave's 16 q-rows (each async16 = one 1KB row)
#pragma unroll
    for (int i = 0; i < 16; ++i) {
        int row = __shfl(qv, i, 64);
        async16((const ushort_t*)(q_tab + (size_t)row * 256) + lane * 8,
                sQ + (w * 16 + i) * 520);
    }
    __syncthreads();  // q-rows + sdiv + sLogit ready (barrier drains vmcnt)
    // ---- phase 2: fragments into registers (sQ live)
    uint4 hvA[8], lvA[8];
    const char* myrow = (const char*)sQ + (w * 16 + pl) * 1040;
    const float* rrow = r_tab + (size_t)rr * 256;
#pragma unroll
    for (int it = 0; it < 8; ++it) {
        int kc = it * 4 + kq;
        int k0 = kc * 8;
        float4 qa = *(const float4*)(myrow + kc * 32);
        float4 qb = *(const float4*)(myrow + kc * 32 + 16);
        float4 ra = *(const float4*)(rrow + kc * 8);
        float4 rb = *(const float4*)(rrow + kc * 8 + 4);
        float v[8] = {qa.x + ra.x, qa.y + ra.y, qa.z + ra.z, qa.w + ra.w,
                      qb.x + rb.x, qb.y + rb.y, qb.z + rb.z, qb.w + rb.w};
        bool iscos = (kc >= 16);
#pragma unroll
        for (int j = 0; j < 8; ++j) {
            float ang = tt * sdiv[(k0 + j) & 127];
            v[j] += iscos ? __cosf(ang) : __sinf(ang);
        }
        ushort_t hs[8], ls[8];
#pragma unroll
        for (int j = 0; j < 8; ++j) {
            ushort_t h = f2bf(v[j]);
            hs[j] = h;
            ls[j] = f2bf(v[j] - bf2f(h));
        }
        uint4 hv, lv;
        hv.x = hs[0] | ((uint_t)hs[1] << 16); hv.y = hs[2] | ((uint_t)hs[3] << 16);
        hv.z = hs[4] | ((uint_t)hs[5] << 16); hv.w = hs[6] | ((uint_t)hs[7] << 16);
        lv.x = ls[0] | ((uint_t)ls[1] << 16); lv.y = ls[2] | ((uint_t)ls[3] << 16);
        lv.z = ls[4] | ((uint_t)ls[5] << 16); lv.w = ls[6] | ((uint_t)ls[7] << 16);
        hvA[it] = hv; lvA[it] = lv;
    }
    __syncthreads();  // all sQ reads complete -> region re-purposed
    // ---- phase 3: fragment exchange
#pragma unroll
    for (int it = 0; it < 8; ++it) {
        int kc = it * 4 + kq;
        int loff = ((w * 32 + kc) * 16 + pl) * 8;
        *(uint4*)(sAhi + loff) = hvA[it];
        *(uint4*)(sAlo + loff) = lvA[it];
    }
    __syncthreads();  // fragments visible block-wide
    // ---- phase 4: struct head (split-bf16, 3 MFMAs), copy-free pipelined B
    {
        f32x4 acc[4][2];
        f32x4 z4 = {0.f, 0.f, 0.f, 0.f};
#pragma unroll
        for (int mt = 0; mt < 4; ++mt)
#pragma unroll
            for (int nt = 0; nt < 2; ++nt) acc[mt][nt] = z4;
        bf16x8 bh[2][2], bl[2][2];
#pragma unroll
        for (int nt = 0; nt < 2; ++nt) {
            int off = (((w * 2 + nt) * 32 + kq) * 16 + nl) * 8;
            bh[0][nt] = *(const bf16x8*)(ws1h + off);
            bl[0][nt] = *(const bf16x8*)(ws1l + off);
        }
#pragma unroll
        for (int ks = 0; ks < 8; ++ks) {
            int cur = ks & 1, nxt = cur ^ 1;
            if (ks < 7) {
#pragma unroll
                for (int nt = 0; nt < 2; ++nt) {
                    int off = (((w * 2 + nt) * 32 + (ks + 1) * 4 + kq) * 16 + nl) * 8;
                    bh[nxt][nt] = *(const bf16x8*)(ws1h + off);
                    bl[nxt][nt] = *(const bf16x8*)(ws1l + off);
                }
            }
            bf16x8 ahi[4], alo[4];
#pragma unroll
            for (int mt = 0; mt < 4; ++mt) {
                int off = ((mt * 32 + ks * 4 + kq) * 16 + nl) * 8;
                ahi[mt] = *(const bf16x8*)&sAhi[off];
                alo[mt] = *(const bf16x8*)&sAlo[off];
            }
#pragma unroll
            for (int mt = 0; mt < 4; ++mt)
#pragma unroll
                for (int nt = 0; nt < 2; ++nt) {
                    acc[mt][nt] = MFMA16(ahi[mt], bh[cur][nt], acc[mt][nt]);
                    acc[mt][nt] = MFMA16(alo[mt], bh[cur][nt], acc[mt][nt]);
                    acc[mt][nt] = MFMA16(ahi[mt], bl[cur][nt], acc[mt][nt]);
                }
        }
        // epilogue: hdn = leaky(acc + const_h); partial logits = hdn * Ws2
        float ps[4][4];
#pragma unroll
        for (int mt = 0; mt < 4; ++mt)
#pragma unroll
            for (int r = 0; r < 4; ++r) ps[mt][r] = 0.f;
#pragma unroll
        for (int nt = 0; nt < 2; ++nt) {
            int ng = w * 32 + nt * 16 + nl;
            float chv = consth[ng], w2 = Ws2[ng];
#pragma unroll
            for (int mt = 0; mt < 4; ++mt)
#pragma unroll
                for (int r = 0; r < 4; ++r) {
                    float v = acc[mt][nt][r] + chv;
                    v = v > 0.f ? v : 0.2f * v;
                    ps[mt][r] += v * w2;
                }
        }
#pragma unroll
        for (int mt = 0; mt < 4; ++mt)
#pragma unroll
            for (int r = 0; r < 4; ++r) {
                float x = ps[mt][r];
                x += __shfl_xor(x, 1, 64);
                x += __shfl_xor(x, 2, 64);
                x += __shfl_xor(x, 4, 64);
                x += __shfl_xor(x, 8, 64);
                ps[mt][r] = x;
            }
        if (nl == 0) {
#pragma unroll
            for (int mt = 0; mt < 4; ++mt)
#pragma unroll
                for (int r = 0; r < 4; ++r)
                    atomicAdd(&sLogit[mt * 16 + kq * 4 + r], ps[mt][r]);
        }
    }
    __syncthreads();
    if (tid < 64) {
        int pp = p0 + tid;
        float lg = sLogit[tid] + bs2[0];
        float y = lg * 100.0f;
        y = fminf(fmaxf(y, -60.f), 60.f);
        float a = 1.0f / (1.0f + expf(-y));
        float av = a * mask[pp];
        out_ahat[pp] = av;
        sAh[tid] = av;
    }
    __syncthreads();  // sAh ready
    // ---- phase 5: Wa GEMM. A-frags (hi) register-resident from LDS; B from L2.
    {
        bf16x8 afr[4][8];
#pragma unroll
        for (int mt = 0; mt < 4; ++mt)
#pragma unroll
            for (int ks = 0; ks < 8; ++ks)
                afr[mt][ks] = *(const bf16x8*)&sAhi[((mt * 32 + ks * 4 + kq) * 16 + nl) * 8];
        int bidx = p0 >> 11;   // sequence index (2048 positions per sequence)
#pragma unroll 1
        for (int nblk = 0; nblk < 4; ++nblk) {
            const ushort_t* gB = wa_b + (size_t)(w * 16 + nblk * 4) * 4096 + lane * 8;
            f32x4 acc[4][4];
            bf16x8 bfr[2][4];
#pragma unroll
            for (int nt = 0; nt < 4; ++nt)
                bfr[0][nt] = *(const bf16x8*)(gB + nt * 4096);
#pragma unroll
            for (int ks = 0; ks < 8; ++ks) {
                int cur = ks & 1, nxt = cur ^ 1;
                if (ks < 7) {
#pragma unroll
                    for (int nt = 0; nt < 4; ++nt)
                        bfr[nxt][nt] = *(const bf16x8*)(gB + nt * 4096 + (ks + 1) * 512);
                }
                if (ks == 0) {
                    f32x4 z4 = {0.f, 0.f, 0.f, 0.f};
#pragma unroll
                    for (int mt = 0; mt < 4; ++mt)
#pragma unroll
                        for (int nt = 0; nt < 4; ++nt)
                            acc[mt][nt] = MFMA16(afr[mt][0], bfr[0][nt], z4);
                } else {
#pragma unroll
                    for (int mt = 0; mt < 4; ++mt)
#pragma unroll
                        for (int nt = 0; nt < 4; ++nt)
                            acc[mt][nt] = MFMA16(afr[mt][ks], bfr[cur][nt], acc[mt][nt]);
                }
            }
            // epilogue: leaky(acc+ba)*A_hat, reduce the 64 m-rows, atomicAdd u_i
#pragma unroll
            for (int nt = 0; nt < 4; ++nt) {
                int ng = w * 256 + nblk * 64 + nt * 16 + nl;
                float ban = ba[ng];
                float s = 0.f;
#pragma unroll
                for (int mt = 0; mt < 4; ++mt)
#pragma unroll
                    for (int r = 0; r < 4; ++r) {
                        float v = acc[mt][nt][r] + ban;
                        v = v > 0.f ? v : 0.2f * v;
                        int ml = mt * 16 + kq * 4 + r;
                        s += v * sAh[ml];
                    }
                s += __shfl_xor(s, 16, 64);
                s += __shfl_xor(s, 32, 64);
                if (kq == 0) atomicAdd(&u_i[bidx * 1024 + ng], s);
            }
        }
    }
}

extern "C" void kernel_launch(void* const* d_in, const int* in_sizes, int n_in,
                              void* d_out, int out_size, void* d_ws, size_t ws_size,
                              hipStream_t stream) {
    const int* q_seq = (const int*)d_in[0];
    const int* r_seq = (const int*)d_in[1];
    const float* t_seq = (const float*)d_in[2];
    const float* mask = (const float*)d_in[3];
    const float* q_tab = (const float*)d_in[4];
    const float* r_tab = (const float*)d_in[5];
    const float* virt = (const float*)d_in[6];
    const float* Ws1 = (const float*)d_in[7];
    const float* bs1 = (const float*)d_in[8];
    const float* Ws2 = (const float*)d_in[9];
    const float* bs2 = (const float*)d_in[10];
    const float* Wa = (const float*)d_in[11];
    const float* ba = (const float*)d_in[12];
    float* out = (float*)d_out;

    // ws layout (h_events no longer materialized!)
    ushort_t* wa_b = (ushort_t*)d_ws;            // 1024*256 bf16 blocked (512 KB)
    ushort_t* ws1h = wa_b + 262144;              // 128*256 bf16 blocked
    ushort_t* ws1l = ws1h + 32768;
    float* ch = (float*)(ws1l + 32768);          // 128 f32

    hipMemsetAsync(out, 0, 65536 * sizeof(float), stream);  // zero u_i
    hipLaunchKernelGGL(k_prep, dim3(145), dim3(256), 0, stream,
                       Ws1, bs1, virt, Wa, ch, wa_b, ws1h, ws1l);
    hipLaunchKernelGGL(k_fused, dim3(2048), dim3(256), 0, stream,
                       q_seq, r_seq, t_seq, q_tab, r_tab, ws1h, ws1l, ch, Ws2, bs2,
                       mask, wa_b, ba, out + 65536, out);
}

// Round 7
// 251.364 us; speedup vs baseline: 1.0463x; 1.0015x over previous
//
#include <hip/hip_runtime.h>

typedef unsigned short ushort_t;
typedef unsigned int uint_t;

typedef short bf16x8 __attribute__((ext_vector_type(8)));
typedef float f32x4 __attribute__((ext_vector_type(4)));

#define MFMA16(a, b, c) __builtin_amdgcn_mfma_f32_16x16x32_bf16(a, b, c, 0, 0, 0)

__device__ __forceinline__ ushort_t f2bf(float f) {
    uint_t u = __float_as_uint(f);
    u += 0x7fffu + ((u >> 16) & 1u);   // RNE
    return (ushort_t)(u >> 16);
}
__device__ __forceinline__ float bf2f(ushort_t h) {
    return __uint_as_float(((uint_t)h) << 16);
}

// ---------------- K0: fused prep. block0: const_h; blocks 1..128: Wa->bf16 blocked;
// blocks 129..144: Ws1[:, :256] -> bf16 hi/lo blocked.
// blocked flat (in 8-elem units): ((row/16)*32 + k/8)*16 + row%16
__global__ void k_prep(const float* __restrict__ Ws1, const float* __restrict__ bs1,
                       const float* __restrict__ virt, const float* __restrict__ Wa,
                       float* __restrict__ consth, ushort_t* __restrict__ wa_b,
                       ushort_t* __restrict__ ws1h, ushort_t* __restrict__ ws1l) {
    int b = blockIdx.x;
    if (b == 0) {
        int h = threadIdx.x;
        if (h < 128) {
            const float* row = Ws1 + h * 512 + 256;
            float s = bs1[h];
            for (int d = 0; d < 256; ++d) s += row[d] * virt[d];
            consth[h] = s;
        }
        return;
    }
    const float* src;
    int src_stride, tid;
    ushort_t *dhi, *dlo;
    if (b <= 128) {
        tid = (b - 1) * 256 + threadIdx.x;   // 1024 rows * 32 = 32768 tids
        src = Wa; src_stride = 256; dhi = wa_b; dlo = nullptr;
    } else {
        tid = (b - 129) * 256 + threadIdx.x; // 128 rows * 32 = 4096 tids
        src = Ws1; src_stride = 512; dhi = ws1h; dlo = ws1l;
    }
    int pl = tid & 15, kc = (tid >> 4) & 31, pt = tid >> 9;
    int row = pt * 16 + pl;
    const float* s = src + (size_t)row * src_stride + kc * 8;
    ushort_t hs[8], ls[8];
#pragma unroll
    for (int j = 0; j < 8; ++j) {
        float v = s[j];
        ushort_t h = f2bf(v);
        hs[j] = h;
        ls[j] = f2bf(v - bf2f(h));
    }
    uint4 hv;
    hv.x = hs[0] | ((uint_t)hs[1] << 16); hv.y = hs[2] | ((uint_t)hs[3] << 16);
    hv.z = hs[4] | ((uint_t)hs[5] << 16); hv.w = hs[6] | ((uint_t)hs[7] << 16);
    *(uint4*)(dhi + (size_t)tid * 8) = hv;
    if (dlo) {
        uint4 lv;
        lv.x = ls[0] | ((uint_t)ls[1] << 16); lv.y = ls[2] | ((uint_t)ls[3] << 16);
        lv.z = ls[4] | ((uint_t)ls[5] << 16); lv.w = ls[6] | ((uint_t)ls[7] << 16);
        *(uint4*)(dlo + (size_t)tid * 8) = lv;
    }
}

// ---------------- K1: FULLY FUSED embed + struct head + Wa-GEMM aggregator.
// Per block: 64 positions, 4 waves. DIRECT per-lane gather (no LDS staging, no
// DMA barrier): lanes sharing pl share a row; the 4 kq-lanes of a pl read one
// contiguous 128B line per iteration. Fragments (MFMA A-layout) are stored
// straight to sAhi|sAlo during compute. Then:
//  - struct head: split-bf16 MFMA (3 terms) + leaky + .Ws2 + sigmoid -> A_hat
//  - Wa GEMM: A-frags reg-resident from LDS, B streamed from L2 (parity dbuf);
//    fused leaky+ba, *A_hat, m-reduce, atomicAdd u_i.
// h_events NEVER touches HBM.
__global__ __launch_bounds__(256, 2) void k_fused(
    const int* __restrict__ q_seq, const int* __restrict__ r_seq,
    const float* __restrict__ t_seq, const float* __restrict__ q_tab,
    const float* __restrict__ r_tab,
    const ushort_t* __restrict__ ws1h, const ushort_t* __restrict__ ws1l,
    const float* __restrict__ consth, const float* __restrict__ Ws2,
    const float* __restrict__ bs2, const float* __restrict__ mask,
    const ushort_t* __restrict__ wa_b, const float* __restrict__ ba,
    float* __restrict__ out_ahat, float* __restrict__ u_i) {
    __shared__ __align__(16) ushort_t sAhi[16384];   // 64 pos x 256 k, blocked
    __shared__ __align__(16) ushort_t sAlo[16384];
    __shared__ float sdiv[128];
    __shared__ float sLogit[64];
    __shared__ float sAh[64];
    int tid = threadIdx.x;
    if (tid < 128) sdiv[tid] = __expf((float)tid * -0.07195578415606394f); // -ln(10000)/128
    if (tid < 64) sLogit[tid] = 0.0f;
    int w = tid >> 6, lane = tid & 63;
    int pl = lane & 15, kq = lane >> 4;
    int nl = pl;
    int p0 = blockIdx.x * 64;
    int p = p0 + w * 16 + pl;
    int qv = q_seq[p];          // lanes with same pl share qv (same p)
    int rr = r_seq[p];
    float tt = t_seq[p];
    const float* grow = q_tab + (size_t)qv * 256;
    const float* rrow = r_tab + (size_t)rr * 256;
    __syncthreads();  // sdiv + sLogit ready
    // ---- gather + trig -> fragments straight into LDS (MFMA A-layout)
#pragma unroll
    for (int it = 0; it < 8; ++it) {
        int kc = it * 4 + kq;
        int k0 = kc * 8;
        float4 qa = *(const float4*)(grow + kc * 8);
        float4 qb = *(const float4*)(grow + kc * 8 + 4);
        float4 ra = *(const float4*)(rrow + kc * 8);
        float4 rb = *(const float4*)(rrow + kc * 8 + 4);
        float v[8] = {qa.x + ra.x, qa.y + ra.y, qa.z + ra.z, qa.w + ra.w,
                      qb.x + rb.x, qb.y + rb.y, qb.z + rb.z, qb.w + rb.w};
        bool iscos = (kc >= 16);
#pragma unroll
        for (int j = 0; j < 8; ++j) {
            float ang = tt * sdiv[(k0 + j) & 127];
            v[j] += iscos ? __cosf(ang) : __sinf(ang);
        }
        ushort_t hs[8], ls[8];
#pragma unroll
        for (int j = 0; j < 8; ++j) {
            ushort_t h = f2bf(v[j]);
            hs[j] = h;
            // lo: truncate (RNE unnecessary: residual is ~2^-9 of hi)
            ls[j] = (ushort_t)(__float_as_uint(v[j] - bf2f(h)) >> 16);
        }
        uint4 hv, lv;
        hv.x = hs[0] | ((uint_t)hs[1] << 16); hv.y = hs[2] | ((uint_t)hs[3] << 16);
        hv.z = hs[4] | ((uint_t)hs[5] << 16); hv.w = hs[6] | ((uint_t)hs[7] << 16);
        lv.x = ls[0] | ((uint_t)ls[1] << 16); lv.y = ls[2] | ((uint_t)ls[3] << 16);
        lv.z = ls[4] | ((uint_t)ls[5] << 16); lv.w = ls[6] | ((uint_t)ls[7] << 16);
        int loff = ((w * 32 + kc) * 16 + pl) * 8;
        *(uint4*)(sAhi + loff) = hv;
        *(uint4*)(sAlo + loff) = lv;
    }
    __syncthreads();  // fragments visible block-wide
    // ---- struct head (split-bf16, 3 MFMAs), copy-free pipelined B from global
    {
        f32x4 acc[4][2];
        f32x4 z4 = {0.f, 0.f, 0.f, 0.f};
#pragma unroll
        for (int mt = 0; mt < 4; ++mt)
#pragma unroll
            for (int nt = 0; nt < 2; ++nt) acc[mt][nt] = z4;
        bf16x8 bh[2][2], bl[2][2];
#pragma unroll
        for (int nt = 0; nt < 2; ++nt) {
            int off = (((w * 2 + nt) * 32 + kq) * 16 + nl) * 8;
            bh[0][nt] = *(const bf16x8*)(ws1h + off);
            bl[0][nt] = *(const bf16x8*)(ws1l + off);
        }
#pragma unroll
        for (int ks = 0; ks < 8; ++ks) {
            int cur = ks & 1, nxt = cur ^ 1;
            if (ks < 7) {
#pragma unroll
                for (int nt = 0; nt < 2; ++nt) {
                    int off = (((w * 2 + nt) * 32 + (ks + 1) * 4 + kq) * 16 + nl) * 8;
                    bh[nxt][nt] = *(const bf16x8*)(ws1h + off);
                    bl[nxt][nt] = *(const bf16x8*)(ws1l + off);
                }
            }
            bf16x8 ahi[4], alo[4];
#pragma unroll
            for (int mt = 0; mt < 4; ++mt) {
                int off = ((mt * 32 + ks * 4 + kq) * 16 + nl) * 8;
                ahi[mt] = *(const bf16x8*)&sAhi[off];
                alo[mt] = *(const bf16x8*)&sAlo[off];
            }
#pragma unroll
            for (int mt = 0; mt < 4; ++mt)
#pragma unroll
                for (int nt = 0; nt < 2; ++nt) {
                    acc[mt][nt] = MFMA16(ahi[mt], bh[cur][nt], acc[mt][nt]);
                    acc[mt][nt] = MFMA16(alo[mt], bh[cur][nt], acc[mt][nt]);
                    acc[mt][nt] = MFMA16(ahi[mt], bl[cur][nt], acc[mt][nt]);
                }
        }
        // epilogue: hdn = leaky(acc + const_h); partial logits = hdn * Ws2
        float ps[4][4];
#pragma unroll
        for (int mt = 0; mt < 4; ++mt)
#pragma unroll
            for (int r = 0; r < 4; ++r) ps[mt][r] = 0.f;
#pragma unroll
        for (int nt = 0; nt < 2; ++nt) {
            int ng = w * 32 + nt * 16 + nl;
            float chv = consth[ng], w2 = Ws2[ng];
#pragma unroll
            for (int mt = 0; mt < 4; ++mt)
#pragma unroll
                for (int r = 0; r < 4; ++r) {
                    float v = acc[mt][nt][r] + chv;
                    v = v > 0.f ? v : 0.2f * v;
                    ps[mt][r] += v * w2;
                }
        }
#pragma unroll
        for (int mt = 0; mt < 4; ++mt)
#pragma unroll
            for (int r = 0; r < 4; ++r) {
                float x = ps[mt][r];
                x += __shfl_xor(x, 1, 64);
                x += __shfl_xor(x, 2, 64);
                x += __shfl_xor(x, 4, 64);
                x += __shfl_xor(x, 8, 64);
                ps[mt][r] = x;
            }
        if (nl == 0) {
#pragma unroll
            for (int mt = 0; mt < 4; ++mt)
#pragma unroll
                for (int r = 0; r < 4; ++r)
                    atomicAdd(&sLogit[mt * 16 + kq * 4 + r], ps[mt][r]);
        }
    }
    __syncthreads();
    if (tid < 64) {
        int pp = p0 + tid;
        float lg = sLogit[tid] + bs2[0];
        float y = lg * 100.0f;
        y = fminf(fmaxf(y, -60.f), 60.f);
        float a = 1.0f / (1.0f + expf(-y));
        float av = a * mask[pp];
        out_ahat[pp] = av;
        sAh[tid] = av;
    }
    __syncthreads();  // sAh ready
    // ---- Wa GEMM. A-frags (hi) register-resident from LDS; B from L2.
    {
        bf16x8 afr[4][8];
#pragma unroll
        for (int mt = 0; mt < 4; ++mt)
#pragma unroll
            for (int ks = 0; ks < 8; ++ks)
                afr[mt][ks] = *(const bf16x8*)&sAhi[((mt * 32 + ks * 4 + kq) * 16 + nl) * 8];
        int bidx = p0 >> 11;   // sequence index (2048 positions per sequence)
#pragma unroll 1
        for (int nblk = 0; nblk < 4; ++nblk) {
            const ushort_t* gB = wa_b + (size_t)(w * 16 + nblk * 4) * 4096 + lane * 8;
            f32x4 acc[4][4];
            bf16x8 bfr[2][4];
#pragma unroll
            for (int nt = 0; nt < 4; ++nt)
                bfr[0][nt] = *(const bf16x8*)(gB + nt * 4096);
#pragma unroll
            for (int ks = 0; ks < 8; ++ks) {
                int cur = ks & 1, nxt = cur ^ 1;
                if (ks < 7) {
#pragma unroll
                    for (int nt = 0; nt < 4; ++nt)
                        bfr[nxt][nt] = *(const bf16x8*)(gB + nt * 4096 + (ks + 1) * 512);
                }
                if (ks == 0) {
                    f32x4 z4 = {0.f, 0.f, 0.f, 0.f};
#pragma unroll
                    for (int mt = 0; mt < 4; ++mt)
#pragma unroll
                        for (int nt = 0; nt < 4; ++nt)
                            acc[mt][nt] = MFMA16(afr[mt][0], bfr[0][nt], z4);
                } else {
#pragma unroll
                    for (int mt = 0; mt < 4; ++mt)
#pragma unroll
                        for (int nt = 0; nt < 4; ++nt)
                            acc[mt][nt] = MFMA16(afr[mt][ks], bfr[cur][nt], acc[mt][nt]);
                }
            }
            // epilogue: leaky(acc+ba)*A_hat, reduce the 64 m-rows, atomicAdd u_i
#pragma unroll
            for (int nt = 0; nt < 4; ++nt) {
                int ng = w * 256 + nblk * 64 + nt * 16 + nl;
                float ban = ba[ng];
                float s = 0.f;
#pragma unroll
                for (int mt = 0; mt < 4; ++mt)
#pragma unroll
                    for (int r = 0; r < 4; ++r) {
                        float v = acc[mt][nt][r] + ban;
                        v = v > 0.f ? v : 0.2f * v;
                        int ml = mt * 16 + kq * 4 + r;
                        s += v * sAh[ml];
                    }
                s += __shfl_xor(s, 16, 64);
                s += __shfl_xor(s, 32, 64);
                if (kq == 0) atomicAdd(&u_i[bidx * 1024 + ng], s);
            }
        }
    }
}

extern "C" void kernel_launch(void* const* d_in, const int* in_sizes, int n_in,
                              void* d_out, int out_size, void* d_ws, size_t ws_size,
                              hipStream_t stream) {
    const int* q_seq = (const int*)d_in[0];
    const int* r_seq = (const int*)d_in[1];
    const float* t_seq = (const float*)d_in[2];
    const float* mask = (const float*)d_in[3];
    const float* q_tab = (const float*)d_in[4];
    const float* r_tab = (const float*)d_in[5];
    const float* virt = (const float*)d_in[6];
    const float* Ws1 = (const float*)d_in[7];
    const float* bs1 = (const float*)d_in[8];
    const float* Ws2 = (const float*)d_in[9];
    const float* bs2 = (const float*)d_in[10];
    const float* Wa = (const float*)d_in[11];
    const float* ba = (const float*)d_in[12];
    float* out = (float*)d_out;

    // ws layout (h_events never materialized)
    ushort_t* wa_b = (ushort_t*)d_ws;            // 1024*256 bf16 blocked (512 KB)
    ushort_t* ws1h = wa_b + 262144;              // 128*256 bf16 blocked
    ushort_t* ws1l = ws1h + 32768;
    float* ch = (float*)(ws1l + 32768);          // 128 f32

    hipMemsetAsync(out, 0, 65536 * sizeof(float), stream);  // zero u_i
    hipLaunchKernelGGL(k_prep, dim3(145), dim3(256), 0, stream,
                       Ws1, bs1, virt, Wa, ch, wa_b, ws1h, ws1l);
    hipLaunchKernelGGL(k_fused, dim3(2048), dim3(256), 0, stream,
                       q_seq, r_seq, t_seq, q_tab, r_tab, ws1h, ws1l, ch, Ws2, bs2,
                       mask, wa_b, ba, out + 65536, out);
}